// Round 8
// baseline (339.761 us; speedup 1.0000x reference)
//
#include <hip/hip_runtime.h>
#include <cstdint>
#include <cstddef>

// EEG_SimpleLSM round 14: barrier-free async pipeline (LDS mailboxes).
// R13 post-mortem: REGRESSED 146.6->196.8us, VALUBusy 48->35%. Moving the x
// stream onto the critical L0u wave made each wave64 dwordx4 splinter into
// ~32 line transactions (16KB inter-lane stride) and put L2 latency inside
// the carried chain. Reverted; loader wave restored. The F+W model stands:
// phase = F(3.6k, alignment cost of __syncthreads) + 40.6*CT (L0 chain).
// R14 deletes F: the stage DAG (loader -> L0u -> [L0r+L1u] -> L1r x2 ->
// L2 x2) with 2-slot rings needs only producer/consumer ordering, not a
// global barrier. Per-edge LDS mailbox flags:
//   producer: sched_barrier(0); s_waitcnt lgkmcnt(0); lane0 ds_write c+1.
//   consumer: spin on volatile broadcast read (s_sleep(1) backoff), then
//             compiler mem-fence + sched_barrier(0) (rule #18 discipline).
// Each wave free-runs; span ~= bottleneck stage total = L0u chain
// (42 x ~4k cyc ~= 170k) + fill. Other stages' DS/VALU hide underneath.
// Also: L0r merged into the L1u wave (R13's sound part — kills the j0r
// edge); CT=96, TS0/TS1 and all stage bodies identical to R12 (absmax 0.0
// arithmetic: carried-select folding, Markstein exact /3, zero-column
// gather, reciprocal-mul /80000).
// Edges/flags: E1 xs(w4->w0): P1,C1 | E2 nv0r(w0->w2): P2,C2 (C2 published
// right after w2's scans to release w0 early) | E4 nv1r(w2->w3,w6): P4,
// C4A,C4B | E5 mpr/jpr half0(w3->w5,w7): P5,C5A,C5B | E6 half1(w6->w5,w7):
// P6,C6A,C6B. w1 idles (exits). Deadlock-free: DAG + credits, waits with
// tgt<=0 short-circuit, counters monotone.

#pragma clang fp contract(off)

typedef float f32x4 __attribute__((ext_vector_type(4)));

constexpr int T_TOTAL = 4000;
constexpr int NCH = 32;
constexpr int N1 = 64;
constexpr int N2 = 128;
constexpr int CT = 96;
constexpr int TS0 = 108;                          // xs [ch][t] stride
constexpr int TS1 = 100;                          // nv rings [n][t] stride
constexpr int NCHUNK = (T_TOTAL + CT - 1) / CT;   // 42 (last chunk = 64 steps)

// mailbox flag indices
constexpr int P1 = 0, C1 = 1, P2 = 2, C2 = 3, P4 = 4, C4A = 5, C4B = 6,
              P5 = 7, C5A = 8, C5B = 9, P6 = 10, C6A = 11, C6B = 12;

__device__ __forceinline__ int read_lane_i(int v, int l) {
  return __builtin_amdgcn_readlane(v, l);
}

__global__ __launch_bounds__(512, 1) void lsm_kernel(
    const float* __restrict__ x, const float* __restrict__ W1,
    const float* __restrict__ W2, float* __restrict__ out) {
  __shared__ float w1s[N1 * 33];        // W1[n][k] at n*33+k; col 32 == 0
  __shared__ float w2s[N2 * 65];        // W2[n][k] at n*65+k; col 64 == 0
  __shared__ float xs[2][NCH * TS0];    // x chunk, [ch][t]
  __shared__ float nv0r[2][NCH * TS1];  // L0 nv ring, [neuron][t]
  __shared__ float nv1r[2][N1 * TS1];   // L1 nv ring, [neuron][t]
  __shared__ float mpr[2][2][CT];       // L1 partial max  [parity][half][step]
  __shared__ int   jpr[2][2][CT];       // L1 partial argj [parity][half][step]
  volatile __shared__ int fl[16];       // mailbox counters

  const int tid = threadIdx.x;
  const int wid = tid >> 6;
  const int lane = tid & 63;
  const int b = blockIdx.x;

  for (int e = tid; e < N1 * NCH; e += 512) w1s[(e >> 5) * 33 + (e & 31)] = W1[e];
  for (int e = tid; e < N2 * N1; e += 512) w2s[(e >> 6) * 65 + (e & 63)] = W2[e];
  if (tid < N1) w1s[tid * 33 + 32] = 0.f;          // zero column
  if (tid < N2) w2s[tid * 65 + 64] = 0.f;          // zero column
  if (tid < 16) fl[tid] = 0;
  __syncthreads();                       // the ONLY barrier in the kernel

  auto wait_ge = [&](int idx, int tgt) {
    if (tgt <= 0) return;
    while (fl[idx] < tgt) __builtin_amdgcn_s_sleep(1);
    asm volatile("" ::: "memory");           // no hoisting of guarded reads
    __builtin_amdgcn_sched_barrier(0);
  };
  auto publish = [&](int idx, int val) {
    __builtin_amdgcn_sched_barrier(0);       // no sinking of data writes
    asm volatile("s_waitcnt lgkmcnt(0)" ::: "memory");  // data visible first
    if (lane == 0) fl[idx] = val;
  };

  const float* xb = x + (size_t)b * (NCH * T_TOTAL);
  constexpr float R3 = 1.0f / 3.0f;                // RN(1/3)
  constexpr float R80 = 1.0f / 80000.0f;

  if (wid == 4) {
    // ================= loader: x chunk c -> xs [ch][t] =================
    const int g8 = lane >> 3;            // channel sub-index 0..7
    const int tl8 = (lane & 7) << 2;     // local t within 32-block
    for (int c = 0; c < NCHUNK; ++c) {
      wait_ge(C1, c - 1);                // slot (c&1) free
      float* dst = xs[c & 1];
      f32x4 vr[12];
      bool okv[12];
#pragma unroll
      for (int j = 0; j < 12; ++j) {
        const int k = (j & 3) * 8 + g8;  // channel
        const int ts = j >> 2;           // t sub-block 0..2
        const int tg = c * CT + ts * 32 + tl8;
        const bool ok = (tg + 3) < T_TOTAL;
        okv[j] = ok;
        const int tgs = ok ? tg : 0;     // clamped, always in-bounds
        vr[j] = *reinterpret_cast<const f32x4*>(&xb[(size_t)k * T_TOTAL + tgs]);
      }
#pragma unroll
      for (int j = 0; j < 12; ++j) {
        if (okv[j]) {
          const int k = (j & 3) * 8 + g8;
          const int ts = j >> 2;
          *(f32x4*)(&dst[k * TS0 + ts * 32 + tl8]) = vr[j];
        }
      }
      publish(P1, c + 1);
    }
  } else if (wid == 0) {
    // ================= L0 update: the carried chain =================
    float nv0p = 0.f;
    const int xl = lane & 31;                  // lanes 32-63 mirror 0-31
    const int hi4 = (lane >> 5) << 2;          // 0 | 4: write-half offset
    for (int c = 0; c < NCHUNK; ++c) {
      wait_ge(P1, c + 1);                      // xs[c&1] ready
      wait_ge(C2, c - 1);                      // nv0r slot free
      const int S = min(CT, T_TOTAL - c * CT);
      const float* xrow = xs[c & 1] + xl * TS0;    // mirror lanes: broadcast
      float* nrow = nv0r[c & 1] + xl * TS1 + hi4;
      f32x4 C0 = *(const f32x4*)(xrow + 0);
      f32x4 Cb = *(const f32x4*)(xrow + 4);
      for (int tb = 0; tb < S; tb += 8) {
        f32x4 N0 = *(const f32x4*)(xrow + tb + 8);   // pad-safe (TS0=108)
        f32x4 Nx = *(const f32x4*)(xrow + tb + 12);
        float nva[8];
#pragma unroll
        for (int k = 0; k < 8; ++k) {
          float xc = (k < 4) ? C0[k] : Cb[k - 4];
          float a  = nv0p + xc;
          float q0 = nv0p * R3;
          float e  = __builtin_fmaf(-3.0f, q0, nv0p);
          float q  = __builtin_fmaf(e, R3, q0);  // == RN(nv0p/3)
          bool  r  = nv0p >= 1.5f;
          float f  = a - q;
          nv0p = r ? xc : f;
          nva[k] = nv0p;
        }
        f32x4 wv;
        wv.x = hi4 ? nva[4] : nva[0];
        wv.y = hi4 ? nva[5] : nva[1];
        wv.z = hi4 ? nva[6] : nva[2];
        wv.w = hi4 ? nva[7] : nva[3];
        *(f32x4*)(nrow + tb) = wv;      // lane l & l+32 cover steps tb..tb+7
        C0 = N0; Cb = Nx;
      }
      publish(P2, c + 1);
      publish(C1, c + 1);                      // release loader slot
    }
  } else if (wid == 2) {
    // ============ L0 reduce + L1 update (merged wave) ============
    float nv1p = 0.f;
    const float* wrow = w1s + lane * 33;
    for (int c = 0; c < NCHUNK; ++c) {
      wait_ge(P2, c + 1);                      // nv0r[c&1] ready
      const int S = min(CT, T_TOTAL - c * CT);
      const int cb = c & 1;
      // scan pass 1: steps 0..63 (step = lane), 32 neurons
      const float* nvs = nv0r[cb] + lane;
      float m = nvs[0];
      int j = 0;
#pragma unroll 8
      for (int n = 1; n < 32; ++n) {
        float v = nvs[n * TS1];
        bool g = v > m;                 // strict: first index kept on ties
        j = g ? n : j;
        m = g ? v : m;
      }
      const int jv = (m >= 1.5f) ? j : 32;     // 32 -> zero col
      // scan pass 2: steps 64..95 (lane<32); others jv2=32 (bounded, dead)
      int jv2 = 32;
      if (lane < 32) {
        const float* nvs2 = nv0r[cb] + 64 + lane;
        float m2 = nvs2[0];
        int j2 = 0;
#pragma unroll 8
        for (int n = 1; n < 32; ++n) {
          float v = nvs2[n * TS1];
          bool g = v > m2;
          j2 = g ? n : j2;
          m2 = g ? v : m2;
        }
        jv2 = (m2 >= 1.5f) ? j2 : 32;
      }
      publish(C2, c + 1);                      // release nv0r slot EARLY
      wait_ge(C4A, c - 1);                     // nv1r slot free (both
      wait_ge(C4B, c - 1);                     //  consumers done with c-2)
      float* nrow = nv1r[cb] + lane * TS1;
      float hr[8];
#pragma unroll
      for (int k = 0; k < 8; ++k) hr[k] = wrow[read_lane_i(jv, k)];
      for (int tb = 0; tb < S; tb += 8) {
        const int pb = tb + 8;          // 8-aligned: never straddles 64
        const bool hi = pb >= 64;
        const int src = hi ? jv2 : jv;
        const int pbase = hi ? pb - 64 : pb;   // overrun lanes: bounded, dead
        float nva[8];
#pragma unroll
        for (int k = 0; k < 8; ++k) {
          float h = hr[k];
          hr[k] = wrow[read_lane_i(src, pbase + k)];
          float a = nv1p + h;
          float mm = nv1p * R80;
          bool  r = nv1p >= 1.2f;
          float f = a - mm;
          nv1p = r ? h : f;
          nva[k] = nv1p;
        }
        f32x4 w0v = {nva[0], nva[1], nva[2], nva[3]};
        f32x4 w1v = {nva[4], nva[5], nva[6], nva[7]};
        *(f32x4*)(nrow + tb) = w0v;
        *(f32x4*)(nrow + tb + 4) = w1v;
      }
      publish(P4, c + 1);
    }
  } else if (wid == 3 || wid == 6) {
    // ================= L1 reduce: neuron half-scan =================
    const int half = (wid == 6) ? 1 : 0;
    const int pMine = (wid == 6) ? P6 : P5;
    const int cMineA = (wid == 6) ? C6A : C5A;
    const int cMineB = (wid == 6) ? C6B : C5B;
    const int cBack = (wid == 6) ? C4B : C4A;
    for (int c = 0; c < NCHUNK; ++c) {
      wait_ge(P4, c + 1);                      // nv1r[c&1] ready
      wait_ge(cMineA, c - 1);                  // mpr/jpr slot free
      wait_ge(cMineB, c - 1);
      const int cb = c & 1;
      const float* nvs = nv1r[cb] + half * 32 * TS1 + lane;
      float m = nvs[0];
      int j = 0;
#pragma unroll 8
      for (int n = 1; n < 32; ++n) {
        float v = nvs[n * TS1];
        bool g = v > m;
        j = g ? n : j;
        m = g ? v : m;
      }
      mpr[cb][half][lane] = m;
      jpr[cb][half][lane] = j;
      if (lane < 32) {                         // steps 64..95
        const float* nvs2 = nvs + 64;
        float m2 = nvs2[0];
        int j2 = 0;
#pragma unroll 8
        for (int n = 1; n < 32; ++n) {
          float v = nvs2[n * TS1];
          bool g = v > m2;
          j2 = g ? n : j2;
          m2 = g ? v : m2;
        }
        mpr[cb][half][64 + lane] = m2;
        jpr[cb][half][64 + lane] = j2;
      }
      publish(pMine, c + 1);
      publish(cBack, c + 1);                   // release nv1r slot
    }
  } else if (wid == 5 || wid == 7) {
    // ================= L2 update: rows 0-63 / 64-127 =================
    float nv2p = 0.f;
    const float* wrow = w2s + (lane + ((wid == 7) ? 64 : 0)) * 65;
    const int c5 = (wid == 7) ? C5B : C5A;
    const int c6 = (wid == 7) ? C6B : C6A;
    for (int c = 0; c < NCHUNK; ++c) {
      wait_ge(P5, c + 1);                      // both halves ready
      wait_ge(P6, c + 1);
      const int S = min(CT, T_TOTAL - c * CT);
      const int cb = c & 1;
      // merge halves; tie -> low half = first index. Pass 1: step = lane
      float mlo = mpr[cb][0][lane], mhi = mpr[cb][1][lane];
      int jlo = jpr[cb][0][lane], jhi = jpr[cb][1][lane];
      bool g = mhi > mlo;
      float mm = g ? mhi : mlo;
      int jj = g ? (jhi + 32) : jlo;
      const int pkv = (mm >= 1.2f) ? jj : 64;          // steps 0..63
      // pass 2: steps 64..95 (dup across lane&31)
      const int l32 = 64 + (lane & 31);
      float mlo2 = mpr[cb][0][l32], mhi2 = mpr[cb][1][l32];
      int jlo2 = jpr[cb][0][l32], jhi2 = jpr[cb][1][l32];
      bool g2 = mhi2 > mlo2;
      float mm2 = g2 ? mhi2 : mlo2;
      int jj2 = g2 ? (jhi2 + 32) : jlo2;
      const int pkv2 = (mm2 >= 1.2f) ? jj2 : 64;       // steps 64..95
      float hr[8];
#pragma unroll
      for (int k = 0; k < 8; ++k) hr[k] = wrow[read_lane_i(pkv, k)];
      for (int tb = 0; tb < S; tb += 8) {
        const int pb = tb + 8;
        const bool hi = pb >= 64;
        const int src = hi ? pkv2 : pkv;
        const int pbase = hi ? pb - 64 : pb;           // overrun: bounded, dead
#pragma unroll
        for (int k = 0; k < 8; ++k) {
          float h = hr[k];
          hr[k] = wrow[read_lane_i(src, pbase + k)];
          float a = nv2p + h;
          float mv = nv2p * R80;
          bool  r = nv2p >= 1.2f;
          float f = a - mv;
          nv2p = r ? h : f;
        }
      }
      publish(c5, c + 1);                      // release both halves' slots
      publish(c6, c + 1);
    }
    // nv2p = pre-reset membrane of the last step == pre_v2
    const int row = lane + ((wid == 7) ? 64 : 0);
    out[(size_t)b * N2 + row] = expf(nv2p);
  }
  // wid == 1: idle — exits immediately (no trailing barrier in kernel)
}

extern "C" void kernel_launch(void* const* d_in, const int* in_sizes, int n_in,
                              void* d_out, int out_size, void* d_ws, size_t ws_size,
                              hipStream_t stream) {
  (void)n_in; (void)out_size; (void)d_ws; (void)ws_size;
  const float* x = (const float*)d_in[0];
  const float* W1 = (const float*)d_in[1];
  const float* W2 = (const float*)d_in[2];
  float* out = (float*)d_out;
  const int B = in_sizes[0] / (NCH * T_TOTAL);  // 256
  lsm_kernel<<<dim3(B), dim3(512), 0, stream>>>(x, W1, W2, out);
}

// Round 9
// 335.244 us; speedup vs baseline: 1.0135x; 1.0135x over previous
//
#include <hip/hip_runtime.h>
#include <cstdint>
#include <cstddef>

// EEG_SimpleLSM round 15: async pipeline, poll-economics fix.
// R14 post-mortem: REGRESSED 146.6->210us, but protocol CORRECT (passed,
// absmax 0.0). Failure mode identified: s_sleep(1)=64cy spin -> 5-6 waiting
// waves issue a ds_read poll every ~64cy ~= 0.5 of the single LDS pipe
// burned on polling — the exact shared resource (~3.6k cyc/chunk of real DS
// service) the async design was meant to overlap. Plus a full lgkmcnt(0)
// drain per publish (2-3x/chunk/wave). Measured 12k cyc/chunk ~= 3.6k/(1-
// 0.5) + drains + handoff. The async premise (span -> max(LDS total, max
// stage) ~= 3.6k/chunk ~= 65-70us) is untested, not refuted.
// R15 — two surgical changes, protocol byte-identical (flags/targets/order
// as validated in R14):
//  (1) s_sleep(8) (~512cy) in the spin: poll traffic 50% -> ~4% of LDS
//      pipe. First while-check is sleep-free -> near-zero added latency on
//      critical edges in steady state.
//  (2) merged dual-flag publishes (w0: P2+C1, w3/w6: pMine+cBack, w5/w7:
//      c5+c6): one sched_barrier + one lgkmcnt(0) drain + two lane-0
//      writes — halves per-chunk drains.
// Decision rule: <=120us async confirmed; 120-145 partial; >=145 revert to
// R12 barrier structure and attack DS op count.
// Stage bodies identical to R12/R14 (absmax 0.0 arithmetic: carried-select
// folding, Markstein exact /3, zero-column gather, reciprocal-mul /80000).
// Edges/flags: E1 xs(w4->w0): P1,C1 | E2 nv0r(w0->w2): P2,C2 (C2 published
// right after w2's scans) | E4 nv1r(w2->w3,w6): P4,C4A,C4B | E5 mpr/jpr
// half0(w3->w5,w7): P5,C5A,C5B | E6 half1(w6->w5,w7): P6,C6A,C6B.
// w1 idles. Deadlock-free: DAG + credits, tgt<=0 short-circuit, monotone.

#pragma clang fp contract(off)

typedef float f32x4 __attribute__((ext_vector_type(4)));

constexpr int T_TOTAL = 4000;
constexpr int NCH = 32;
constexpr int N1 = 64;
constexpr int N2 = 128;
constexpr int CT = 96;
constexpr int TS0 = 108;                          // xs [ch][t] stride
constexpr int TS1 = 100;                          // nv rings [n][t] stride
constexpr int NCHUNK = (T_TOTAL + CT - 1) / CT;   // 42 (last chunk = 64 steps)

// mailbox flag indices
constexpr int P1 = 0, C1 = 1, P2 = 2, C2 = 3, P4 = 4, C4A = 5, C4B = 6,
              P5 = 7, C5A = 8, C5B = 9, P6 = 10, C6A = 11, C6B = 12;

__device__ __forceinline__ int read_lane_i(int v, int l) {
  return __builtin_amdgcn_readlane(v, l);
}

__global__ __launch_bounds__(512, 1) void lsm_kernel(
    const float* __restrict__ x, const float* __restrict__ W1,
    const float* __restrict__ W2, float* __restrict__ out) {
  __shared__ float w1s[N1 * 33];        // W1[n][k] at n*33+k; col 32 == 0
  __shared__ float w2s[N2 * 65];        // W2[n][k] at n*65+k; col 64 == 0
  __shared__ float xs[2][NCH * TS0];    // x chunk, [ch][t]
  __shared__ float nv0r[2][NCH * TS1];  // L0 nv ring, [neuron][t]
  __shared__ float nv1r[2][N1 * TS1];   // L1 nv ring, [neuron][t]
  __shared__ float mpr[2][2][CT];       // L1 partial max  [parity][half][step]
  __shared__ int   jpr[2][2][CT];       // L1 partial argj [parity][half][step]
  volatile __shared__ int fl[16];       // mailbox counters

  const int tid = threadIdx.x;
  const int wid = tid >> 6;
  const int lane = tid & 63;
  const int b = blockIdx.x;

  for (int e = tid; e < N1 * NCH; e += 512) w1s[(e >> 5) * 33 + (e & 31)] = W1[e];
  for (int e = tid; e < N2 * N1; e += 512) w2s[(e >> 6) * 65 + (e & 63)] = W2[e];
  if (tid < N1) w1s[tid * 33 + 32] = 0.f;          // zero column
  if (tid < N2) w2s[tid * 65 + 64] = 0.f;          // zero column
  if (tid < 16) fl[tid] = 0;
  __syncthreads();                       // the ONLY barrier in the kernel

  auto wait_ge = [&](int idx, int tgt) {
    if (tgt <= 0) return;
    while (fl[idx] < tgt) __builtin_amdgcn_s_sleep(8);   // ~512cy backoff
    asm volatile("" ::: "memory");           // no hoisting of guarded reads
    __builtin_amdgcn_sched_barrier(0);
  };
  auto publish = [&](int idx, int val) {
    __builtin_amdgcn_sched_barrier(0);       // no sinking of data writes
    asm volatile("s_waitcnt lgkmcnt(0)" ::: "memory");  // data visible first
    if (lane == 0) fl[idx] = val;
  };
  auto publish2 = [&](int idxA, int idxB, int val) {   // merged drain
    __builtin_amdgcn_sched_barrier(0);
    asm volatile("s_waitcnt lgkmcnt(0)" ::: "memory");
    if (lane == 0) { fl[idxA] = val; fl[idxB] = val; }
  };

  const float* xb = x + (size_t)b * (NCH * T_TOTAL);
  constexpr float R3 = 1.0f / 3.0f;                // RN(1/3)
  constexpr float R80 = 1.0f / 80000.0f;

  if (wid == 4) {
    // ================= loader: x chunk c -> xs [ch][t] =================
    const int g8 = lane >> 3;            // channel sub-index 0..7
    const int tl8 = (lane & 7) << 2;     // local t within 32-block
    for (int c = 0; c < NCHUNK; ++c) {
      wait_ge(C1, c - 1);                // slot (c&1) free
      float* dst = xs[c & 1];
      f32x4 vr[12];
      bool okv[12];
#pragma unroll
      for (int j = 0; j < 12; ++j) {
        const int k = (j & 3) * 8 + g8;  // channel
        const int ts = j >> 2;           // t sub-block 0..2
        const int tg = c * CT + ts * 32 + tl8;
        const bool ok = (tg + 3) < T_TOTAL;
        okv[j] = ok;
        const int tgs = ok ? tg : 0;     // clamped, always in-bounds
        vr[j] = *reinterpret_cast<const f32x4*>(&xb[(size_t)k * T_TOTAL + tgs]);
      }
#pragma unroll
      for (int j = 0; j < 12; ++j) {
        if (okv[j]) {
          const int k = (j & 3) * 8 + g8;
          const int ts = j >> 2;
          *(f32x4*)(&dst[k * TS0 + ts * 32 + tl8]) = vr[j];
        }
      }
      publish(P1, c + 1);
    }
  } else if (wid == 0) {
    // ================= L0 update: the carried chain =================
    float nv0p = 0.f;
    const int xl = lane & 31;                  // lanes 32-63 mirror 0-31
    const int hi4 = (lane >> 5) << 2;          // 0 | 4: write-half offset
    for (int c = 0; c < NCHUNK; ++c) {
      wait_ge(P1, c + 1);                      // xs[c&1] ready
      wait_ge(C2, c - 1);                      // nv0r slot free
      const int S = min(CT, T_TOTAL - c * CT);
      const float* xrow = xs[c & 1] + xl * TS0;    // mirror lanes: broadcast
      float* nrow = nv0r[c & 1] + xl * TS1 + hi4;
      f32x4 C0 = *(const f32x4*)(xrow + 0);
      f32x4 Cb = *(const f32x4*)(xrow + 4);
      for (int tb = 0; tb < S; tb += 8) {
        f32x4 N0 = *(const f32x4*)(xrow + tb + 8);   // pad-safe (TS0=108)
        f32x4 Nx = *(const f32x4*)(xrow + tb + 12);
        float nva[8];
#pragma unroll
        for (int k = 0; k < 8; ++k) {
          float xc = (k < 4) ? C0[k] : Cb[k - 4];
          float a  = nv0p + xc;
          float q0 = nv0p * R3;
          float e  = __builtin_fmaf(-3.0f, q0, nv0p);
          float q  = __builtin_fmaf(e, R3, q0);  // == RN(nv0p/3)
          bool  r  = nv0p >= 1.5f;
          float f  = a - q;
          nv0p = r ? xc : f;
          nva[k] = nv0p;
        }
        f32x4 wv;
        wv.x = hi4 ? nva[4] : nva[0];
        wv.y = hi4 ? nva[5] : nva[1];
        wv.z = hi4 ? nva[6] : nva[2];
        wv.w = hi4 ? nva[7] : nva[3];
        *(f32x4*)(nrow + tb) = wv;      // lane l & l+32 cover steps tb..tb+7
        C0 = N0; Cb = Nx;
      }
      publish2(P2, C1, c + 1);                 // nv0r ready + xs slot free
    }
  } else if (wid == 2) {
    // ============ L0 reduce + L1 update (merged wave) ============
    float nv1p = 0.f;
    const float* wrow = w1s + lane * 33;
    for (int c = 0; c < NCHUNK; ++c) {
      wait_ge(P2, c + 1);                      // nv0r[c&1] ready
      const int S = min(CT, T_TOTAL - c * CT);
      const int cb = c & 1;
      // scan pass 1: steps 0..63 (step = lane), 32 neurons
      const float* nvs = nv0r[cb] + lane;
      float m = nvs[0];
      int j = 0;
#pragma unroll 8
      for (int n = 1; n < 32; ++n) {
        float v = nvs[n * TS1];
        bool g = v > m;                 // strict: first index kept on ties
        j = g ? n : j;
        m = g ? v : m;
      }
      const int jv = (m >= 1.5f) ? j : 32;     // 32 -> zero col
      // scan pass 2: steps 64..95 (lane<32); others jv2=32 (bounded, dead)
      int jv2 = 32;
      if (lane < 32) {
        const float* nvs2 = nv0r[cb] + 64 + lane;
        float m2 = nvs2[0];
        int j2 = 0;
#pragma unroll 8
        for (int n = 1; n < 32; ++n) {
          float v = nvs2[n * TS1];
          bool g = v > m2;
          j2 = g ? n : j2;
          m2 = g ? v : m2;
        }
        jv2 = (m2 >= 1.5f) ? j2 : 32;
      }
      publish(C2, c + 1);                      // release nv0r slot EARLY
      wait_ge(C4A, c - 1);                     // nv1r slot free (both
      wait_ge(C4B, c - 1);                     //  consumers done with c-2)
      float* nrow = nv1r[cb] + lane * TS1;
      float hr[8];
#pragma unroll
      for (int k = 0; k < 8; ++k) hr[k] = wrow[read_lane_i(jv, k)];
      for (int tb = 0; tb < S; tb += 8) {
        const int pb = tb + 8;          // 8-aligned: never straddles 64
        const bool hi = pb >= 64;
        const int src = hi ? jv2 : jv;
        const int pbase = hi ? pb - 64 : pb;   // overrun lanes: bounded, dead
        float nva[8];
#pragma unroll
        for (int k = 0; k < 8; ++k) {
          float h = hr[k];
          hr[k] = wrow[read_lane_i(src, pbase + k)];
          float a = nv1p + h;
          float mm = nv1p * R80;
          bool  r = nv1p >= 1.2f;
          float f = a - mm;
          nv1p = r ? h : f;
          nva[k] = nv1p;
        }
        f32x4 w0v = {nva[0], nva[1], nva[2], nva[3]};
        f32x4 w1v = {nva[4], nva[5], nva[6], nva[7]};
        *(f32x4*)(nrow + tb) = w0v;
        *(f32x4*)(nrow + tb + 4) = w1v;
      }
      publish(P4, c + 1);
    }
  } else if (wid == 3 || wid == 6) {
    // ================= L1 reduce: neuron half-scan =================
    const int half = (wid == 6) ? 1 : 0;
    const int pMine = (wid == 6) ? P6 : P5;
    const int cMineA = (wid == 6) ? C6A : C5A;
    const int cMineB = (wid == 6) ? C6B : C5B;
    const int cBack = (wid == 6) ? C4B : C4A;
    for (int c = 0; c < NCHUNK; ++c) {
      wait_ge(P4, c + 1);                      // nv1r[c&1] ready
      wait_ge(cMineA, c - 1);                  // mpr/jpr slot free
      wait_ge(cMineB, c - 1);
      const int cb = c & 1;
      const float* nvs = nv1r[cb] + half * 32 * TS1 + lane;
      float m = nvs[0];
      int j = 0;
#pragma unroll 8
      for (int n = 1; n < 32; ++n) {
        float v = nvs[n * TS1];
        bool g = v > m;
        j = g ? n : j;
        m = g ? v : m;
      }
      mpr[cb][half][lane] = m;
      jpr[cb][half][lane] = j;
      if (lane < 32) {                         // steps 64..95
        const float* nvs2 = nvs + 64;
        float m2 = nvs2[0];
        int j2 = 0;
#pragma unroll 8
        for (int n = 1; n < 32; ++n) {
          float v = nvs2[n * TS1];
          bool g = v > m2;
          j2 = g ? n : j2;
          m2 = g ? v : m2;
        }
        mpr[cb][half][64 + lane] = m2;
        jpr[cb][half][64 + lane] = j2;
      }
      publish2(pMine, cBack, c + 1);           // halves ready + nv1r free
    }
  } else if (wid == 5 || wid == 7) {
    // ================= L2 update: rows 0-63 / 64-127 =================
    float nv2p = 0.f;
    const float* wrow = w2s + (lane + ((wid == 7) ? 64 : 0)) * 65;
    const int c5 = (wid == 7) ? C5B : C5A;
    const int c6 = (wid == 7) ? C6B : C6A;
    for (int c = 0; c < NCHUNK; ++c) {
      wait_ge(P5, c + 1);                      // both halves ready
      wait_ge(P6, c + 1);
      const int S = min(CT, T_TOTAL - c * CT);
      const int cb = c & 1;
      // merge halves; tie -> low half = first index. Pass 1: step = lane
      float mlo = mpr[cb][0][lane], mhi = mpr[cb][1][lane];
      int jlo = jpr[cb][0][lane], jhi = jpr[cb][1][lane];
      bool g = mhi > mlo;
      float mm = g ? mhi : mlo;
      int jj = g ? (jhi + 32) : jlo;
      const int pkv = (mm >= 1.2f) ? jj : 64;          // steps 0..63
      // pass 2: steps 64..95 (dup across lane&31)
      const int l32 = 64 + (lane & 31);
      float mlo2 = mpr[cb][0][l32], mhi2 = mpr[cb][1][l32];
      int jlo2 = jpr[cb][0][l32], jhi2 = jpr[cb][1][l32];
      bool g2 = mhi2 > mlo2;
      float mm2 = g2 ? mhi2 : mlo2;
      int jj2 = g2 ? (jhi2 + 32) : jlo2;
      const int pkv2 = (mm2 >= 1.2f) ? jj2 : 64;       // steps 64..95
      float hr[8];
#pragma unroll
      for (int k = 0; k < 8; ++k) hr[k] = wrow[read_lane_i(pkv, k)];
      for (int tb = 0; tb < S; tb += 8) {
        const int pb = tb + 8;
        const bool hi = pb >= 64;
        const int src = hi ? pkv2 : pkv;
        const int pbase = hi ? pb - 64 : pb;           // overrun: bounded, dead
#pragma unroll
        for (int k = 0; k < 8; ++k) {
          float h = hr[k];
          hr[k] = wrow[read_lane_i(src, pbase + k)];
          float a = nv2p + h;
          float mv = nv2p * R80;
          bool  r = nv2p >= 1.2f;
          float f = a - mv;
          nv2p = r ? h : f;
        }
      }
      publish2(c5, c6, c + 1);                 // release both halves' slots
    }
    // nv2p = pre-reset membrane of the last step == pre_v2
    const int row = lane + ((wid == 7) ? 64 : 0);
    out[(size_t)b * N2 + row] = expf(nv2p);
  }
  // wid == 1: idle — exits immediately (no trailing barrier in kernel)
}

extern "C" void kernel_launch(void* const* d_in, const int* in_sizes, int n_in,
                              void* d_out, int out_size, void* d_ws, size_t ws_size,
                              hipStream_t stream) {
  (void)n_in; (void)out_size; (void)d_ws; (void)ws_size;
  const float* x = (const float*)d_in[0];
  const float* W1 = (const float*)d_in[1];
  const float* W2 = (const float*)d_in[2];
  float* out = (float*)d_out;
  const int B = in_sizes[0] / (NCH * T_TOTAL);  // 256
  lsm_kernel<<<dim3(B), dim3(512), 0, stream>>>(x, W1, W2, out);
}